// Round 3
// 774.225 us; speedup vs baseline: 1.0337x; 1.0337x over previous
//
#include <hip/hip_runtime.h>

typedef _Float16 f16;
typedef _Float16 f16x4 __attribute__((ext_vector_type(4)));
typedef _Float16 f16x8 __attribute__((ext_vector_type(8)));
typedef float f32x4 __attribute__((ext_vector_type(4)));

#define TK 4096      // tokens
#define CD 1024      // C
#define HD 2736      // H
#define HP 2816      // H padded to 22*128
#define MT 104       // max M tiles: sum ceil(cnt_e/128) <= 72, + 32 shared
#define RC 13312     // MT*128 slot rows

// async global->LDS, 16B per lane, lds dest = wave-uniform base + lane*16
#define GLDS16(ldsp, gp) __builtin_amdgcn_global_load_lds( \
    (const __attribute__((address_space(1))) unsigned int*)(gp), \
    (__attribute__((address_space(3))) unsigned int*)(ldsp), 16, 0, 0)

// ---- workspace layout (bytes) ----
static constexpr size_t WS_XB  = 0;                               // f16 x (8.4 MB)
static constexpr size_t WS_H   = WS_XB  + (size_t)TK*CD*2;        // f16 h (75 MB)
static constexpr size_t WS_WGT = WS_H   + (size_t)RC*HP*2;        // f16 [8][HP][CD]
static constexpr size_t WS_WUT = WS_WGT + (size_t)8*HP*CD*2;
static constexpr size_t WS_WDT = WS_WUT + (size_t)8*HP*CD*2;      // f16 [8][CD][HP]
static constexpr size_t WS_SGT = WS_WDT + (size_t)8*CD*HP*2;      // f16 [HP][CD]
static constexpr size_t WS_SUT = WS_SGT + (size_t)HP*CD*2;
static constexpr size_t WS_SDT = WS_SUT + (size_t)HP*CD*2;        // f16 [CD][HP]
static constexpr size_t WS_CT  = WS_SDT + (size_t)CD*HP*2;        // control block
// obuf (fp32 [RC][CD], 54.5 MB) aliases wgt+wut (92 MB) — dead after ffn1
static constexpr size_t WS_OBUF = WS_WGT;
static constexpr size_t CT_STOK = 0;                         // int[RC]
static constexpr size_t CT_SW   = CT_STOK + (size_t)RC*4;    // float[RC]
static constexpr size_t CT_TI   = CT_SW   + (size_t)RC*4;    // int[TK*2]
static constexpr size_t CT_TW   = CT_TI   + (size_t)TK*2*4;  // float[TK*2]
static constexpr size_t CT_ISL  = CT_TW   + (size_t)TK*2*4;  // int[TK*2] inverse slot map
static constexpr size_t CT_CNT  = CT_ISL  + (size_t)TK*2*4;  // int[8]
static constexpr size_t CT_PS   = CT_CNT  + 32;              // float[8]
static constexpr size_t CT_CUR  = CT_PS   + 32;              // int[8]
static constexpr size_t CT_OFF  = CT_CUR  + 32;              // int[10]
static constexpr size_t CT_SIZE = CT_OFF  + 64;

// ---------------- weight convert+transpose, register-only ----------------
// src fp32 [R][Cc] -> dst f16 [Cp][Rp], zero-padded. Block covers dst
// 128 rows (cc) x 64 cols (rr). Lane: 8 coalesced float4 loads, register
// transpose, 4 f16x8 stores. grid.z multiplexes experts (+1 shared slab).
__global__ __launch_bounds__(256) void k_tr(
    const float* __restrict__ srcMain, f16* __restrict__ dstMain,
    const float* __restrict__ srcSh,   f16* __restrict__ dstSh,
    int R, int Cc, int Rp, int Cp, int nMain,
    size_t sstride, size_t dstride) {
    const float* src; f16* dst;
    if ((int)blockIdx.z < nMain) {
        src = srcMain + (size_t)blockIdx.z * sstride;
        dst = dstMain + (size_t)blockIdx.z * dstride;
    } else {
        src = srcSh; dst = dstSh;
    }
    const int tid = threadIdx.x;
    const int l = tid & 63, w = tid >> 6;
    const int cc0 = blockIdx.x * 128 + w * 32 + (l >> 3) * 4;   // dst row = src col
    const int rr0 = blockIdx.y * 64 + (l & 7) * 8;              // dst col = src row
    float4 v[8];
    #pragma unroll
    for (int e = 0; e < 8; e++) {
        int gr = rr0 + e;
        if (gr < R && cc0 + 3 < Cc) {
            v[e] = *(const float4*)(src + (size_t)gr * Cc + cc0);
        } else {
            float* ve = (float*)&v[e];
            #pragma unroll
            for (int c = 0; c < 4; c++)
                ve[c] = (gr < R && cc0 + c < Cc) ? src[(size_t)gr * Cc + cc0 + c] : 0.f;
        }
    }
    #pragma unroll
    for (int c = 0; c < 4; c++) {
        const float* vp = (const float*)v;
        f16x8 o = { (f16)vp[0*4+c], (f16)vp[1*4+c], (f16)vp[2*4+c], (f16)vp[3*4+c],
                    (f16)vp[4*4+c], (f16)vp[5*4+c], (f16)vp[6*4+c], (f16)vp[7*4+c] };
        *(f16x8*)(dst + (size_t)(cc0 + c) * Rp + rr0) = o;
    }
}

// ---------------- router (fp32) + x->f16 cast fused ----------------
__global__ void k_router(const float* __restrict__ x, const float* __restrict__ rw,
                         f16* __restrict__ xb,
                         int* __restrict__ topi, float* __restrict__ topw,
                         int* __restrict__ cnt, float* __restrict__ psum) {
    __shared__ float pl[8];
    int tid = threadIdx.x;
    if (tid < 8) pl[tid] = 0.f;
    __syncthreads();
    int wave = tid >> 6, lane = tid & 63;
    int t = blockIdx.x * 4 + wave;
    float acc[8];
    #pragma unroll
    for (int e = 0; e < 8; e++) acc[e] = 0.f;
    const float* xr = x + (size_t)t * CD;
    f16* xbr = xb + (size_t)t * CD;
    for (int i = 0; i < CD / 64; i++) {
        int c = lane + i * 64;
        float xv = xr[c];
        xbr[c] = (f16)xv;                       // fused cast
        const float* wr = rw + c * 8;
        #pragma unroll
        for (int e = 0; e < 8; e++) acc[e] = fmaf(xv, wr[e], acc[e]);
    }
    #pragma unroll
    for (int e = 0; e < 8; e++) {
        #pragma unroll
        for (int off = 32; off; off >>= 1) acc[e] += __shfl_xor(acc[e], off);
    }
    if (lane == 0) {
        float v1 = -1e30f; int i1 = 0;
        #pragma unroll
        for (int e = 0; e < 8; e++) if (acc[e] > v1) { v1 = acc[e]; i1 = e; }
        float v2 = -1e30f; int i2 = (i1 == 0) ? 1 : 0;
        #pragma unroll
        for (int e = 0; e < 8; e++) if (e != i1 && acc[e] > v2) { v2 = acc[e]; i2 = e; }
        float b = expf(v2 - v1);
        float w1 = 1.f / (1.f + b);
        topi[t*2] = i1; topi[t*2+1] = i2;
        topw[t*2] = w1; topw[t*2+1] = b * w1;
        atomicAdd(&cnt[i1], 1);
        atomicAdd(&cnt[i2], 1);
        float m = acc[0];
        #pragma unroll
        for (int e = 1; e < 8; e++) m = fmaxf(m, acc[e]);
        float pe[8]; float s = 0.f;
        #pragma unroll
        for (int e = 0; e < 8; e++) { pe[e] = expf(acc[e] - m); s += pe[e]; }
        float inv = 1.f / s;
        #pragma unroll
        for (int e = 0; e < 8; e++) atomicAdd(&pl[e], pe[e] * inv);
    }
    __syncthreads();
    if (tid < 8) atomicAdd(&psum[tid], pl[tid]);
}

// ---------------- prefix: 128-aligned expert offsets ----------------
__global__ void k_prefix(const int* __restrict__ cnt, int* __restrict__ cur,
                         int* __restrict__ offs) {
    if (threadIdx.x == 0 && blockIdx.x == 0) {
        int off = 0;
        for (int e = 0; e < 8; e++) {
            offs[e] = off; cur[e] = off;
            off += (cnt[e] + 127) & ~127;
        }
        offs[8] = off;
        offs[9] = RC;
    }
}

// ---------------- scatter tokens into slots (+ inverse map) ----------------
__global__ void k_scatter(const int* __restrict__ topi, const float* __restrict__ topw,
                          int* __restrict__ cur, const int* __restrict__ offs,
                          int* __restrict__ stok, float* __restrict__ sw,
                          int* __restrict__ islot) {
    int t = blockIdx.x * 256 + threadIdx.x;
    if (t >= TK) return;
    #pragma unroll
    for (int s = 0; s < 2; s++) {
        int e = topi[t*2 + s];
        int pos = atomicAdd(&cur[e], 1);
        stok[pos] = t;
        sw[pos] = topw[t*2 + s];
        islot[t*2 + s] = pos;
    }
    int base = offs[8];
    stok[base + t] = t;
    sw[base + t] = 1.0f;
}

// ---------------- ffn1: fused gate+up GEMM + SwiGLU -> h (f16) ----------------
// BK=64, XOR-swizzled LDS (rows of 128B = 8 x 16B slots).
// Write side: global_load_lds writes LDS linearly (lane -> base + lane*16),
// so the swizzle is applied to the per-lane GLOBAL source slot:
//   slot_fetched(lane) = (lane&7) ^ (lane>>3), with row&7 == lane>>3.
// Read side: phys_slot = logical_slot ^ (row&7). Involution -> consistent.
// With 128B rows every row starts at bank 0, so unswizzled reads would be
// 16-way conflicted; swizzled reads spread 16 lanes over 8 bank-quads (2-way
// = free, m136).
__global__ __launch_bounds__(256, 2) void k_ffn1(
    const f16* __restrict__ xb, const f16* __restrict__ wgt,
    const f16* __restrict__ wut, const f16* __restrict__ sgt,
    const f16* __restrict__ sut, const int* __restrict__ offs,
    const int* __restrict__ cnt, const int* __restrict__ stok,
    f16* __restrict__ hbuf)
{
    __shared__ f16 As[128*64];
    __shared__ f16 Bg[128*64];
    __shared__ f16 Bu[128*64];

    const int n0 = blockIdx.x * 128;
    const int m0 = blockIdx.y * 128;
    int g = 0;
    while (g < 8 && m0 >= offs[g+1]) g++;
    if (m0 >= offs[8] + TK) return;
    if (g < 8 && (m0 - offs[g]) >= cnt[g]) return;

    const f16* __restrict__ Wg = (g < 8) ? wgt + (size_t)g * HP * CD : sgt;
    const f16* __restrict__ Wu = (g < 8) ? wut + (size_t)g * HP * CD : sut;

    const int tid = threadIdx.x;
    const int lane = tid & 63;
    const int w = tid >> 6;
    const int w32 = w * 32;

    // per-lane swizzled source offset (halfwords): slot = (lane&7)^(lane>>3)
    const int asw = (((lane & 7) ^ (lane >> 3)) << 3);
    // A: 4 gathered token-row offsets (8 rows per GLDS16, lane>>3 = row in group)
    int rA[4];
    #pragma unroll
    for (int i = 0; i < 4; i++)
        rA[i] = stok[m0 + w32 + 8*i + (lane >> 3)] * CD + asw;
    // B: contiguous weight rows
    const int rB = (n0 + w32 + (lane >> 3)) * CD + asw;

    f32x4 accg[4][4], accu[4][4];
    #pragma unroll
    for (int i = 0; i < 4; i++)
        #pragma unroll
        for (int j = 0; j < 4; j++)
            #pragma unroll
            for (int r = 0; r < 4; r++) { accg[i][j][r] = 0.f; accu[i][j][r] = 0.f; }

    const int wm = (w >> 1) * 64;
    const int wn = (w & 1) * 64;
    const int fm = lane & 15;
    const int fq = lane >> 4;
    const int fs = fm & 7;          // row&7 for all fragment rows this lane reads

    for (int k0 = 0; k0 < CD; k0 += 64) {
        #pragma unroll
        for (int i = 0; i < 4; i++) {
            GLDS16(&As[(w32 + 8*i) * 64], xb + rA[i] + k0);
            GLDS16(&Bg[(w32 + 8*i) * 64], Wg + rB + i*8*CD + k0);
            GLDS16(&Bu[(w32 + 8*i) * 64], Wu + rB + i*8*CD + k0);
        }
        __syncthreads();
        #pragma unroll
        for (int kk = 0; kk < 2; kk++) {
            const int sw = ((((kk << 2) | fq) ^ fs) << 3);   // swizzled k-slot
            f16x8 af[4];
            #pragma unroll
            for (int mi = 0; mi < 4; mi++)
                af[mi] = *(const f16x8*)&As[(wm + mi*16 + fm) * 64 + sw];
            #pragma unroll
            for (int ni = 0; ni < 4; ni++) {
                f16x8 bgf = *(const f16x8*)&Bg[(wn + ni*16 + fm) * 64 + sw];
                f16x8 bur = *(const f16x8*)&Bu[(wn + ni*16 + fm) * 64 + sw];
                #pragma unroll
                for (int mi = 0; mi < 4; mi++) {
                    accg[mi][ni] = __builtin_amdgcn_mfma_f32_16x16x32_f16(af[mi], bgf, accg[mi][ni], 0, 0, 0);
                    accu[mi][ni] = __builtin_amdgcn_mfma_f32_16x16x32_f16(af[mi], bur, accu[mi][ni], 0, 0, 0);
                }
            }
        }
        __syncthreads();
    }

    #pragma unroll
    for (int mi = 0; mi < 4; mi++) {
        #pragma unroll
        for (int ni = 0; ni < 4; ni++) {
            #pragma unroll
            for (int r = 0; r < 4; r++) {
                int row = m0 + wm + mi*16 + fq*4 + r;
                int col = n0 + wn + ni*16 + fm;
                float gv = accg[mi][ni][r];
                float uv = accu[mi][ni][r];
                float hv = gv / (1.f + __expf(-gv)) * uv;
                hbuf[(size_t)row * HP + col] = (f16)hv;
            }
        }
    }
}

// ---------------- ffn2: down GEMM -> per-slot obuf (no atomics) ----------------
// Same BK=64 + XOR-swizzle scheme as k_ffn1.
__global__ __launch_bounds__(256, 2) void k_ffn2(
    const f16* __restrict__ hbuf, const f16* __restrict__ wdt,
    const f16* __restrict__ sdt, const int* __restrict__ offs,
    const int* __restrict__ cnt, float* __restrict__ obuf)
{
    __shared__ f16 As[128*64];
    __shared__ f16 Bs[128*64];

    const int n0 = blockIdx.x * 128;
    const int m0 = blockIdx.y * 128;
    int g = 0;
    while (g < 8 && m0 >= offs[g+1]) g++;
    if (m0 >= offs[8] + TK) return;
    if (g < 8 && (m0 - offs[g]) >= cnt[g]) return;
    const f16* __restrict__ W = (g < 8) ? wdt + (size_t)g * CD * HP : sdt;

    const int tid = threadIdx.x;
    const int lane = tid & 63;
    const int w = tid >> 6;
    const int w32 = w * 32;

    const int asw = (((lane & 7) ^ (lane >> 3)) << 3);
    const int rA = (m0 + w32 + (lane >> 3)) * HP + asw;
    const int rB = (n0 + w32 + (lane >> 3)) * HP + asw;

    f32x4 acc[4][4];
    #pragma unroll
    for (int i = 0; i < 4; i++)
        #pragma unroll
        for (int j = 0; j < 4; j++)
            #pragma unroll
            for (int r = 0; r < 4; r++) acc[i][j][r] = 0.f;

    const int wm = (w >> 1) * 64;
    const int wn = (w & 1) * 64;
    const int fm = lane & 15;
    const int fq = lane >> 4;
    const int fs = fm & 7;

    for (int k0 = 0; k0 < HP; k0 += 64) {
        #pragma unroll
        for (int i = 0; i < 4; i++) {
            GLDS16(&As[(w32 + 8*i) * 64], hbuf + (size_t)rA + i*8*HP + k0);
            GLDS16(&Bs[(w32 + 8*i) * 64], W    + (size_t)rB + i*8*HP + k0);
        }
        __syncthreads();
        #pragma unroll
        for (int kk = 0; kk < 2; kk++) {
            const int sw = ((((kk << 2) | fq) ^ fs) << 3);
            f16x8 af[4];
            #pragma unroll
            for (int mi = 0; mi < 4; mi++)
                af[mi] = *(const f16x8*)&As[(wm + mi*16 + fm) * 64 + sw];
            #pragma unroll
            for (int ni = 0; ni < 4; ni++) {
                f16x8 bfr = *(const f16x8*)&Bs[(wn + ni*16 + fm) * 64 + sw];
                #pragma unroll
                for (int mi = 0; mi < 4; mi++)
                    acc[mi][ni] = __builtin_amdgcn_mfma_f32_16x16x32_f16(af[mi], bfr, acc[mi][ni], 0, 0, 0);
            }
        }
        __syncthreads();
    }

    #pragma unroll
    for (int mi = 0; mi < 4; mi++) {
        #pragma unroll
        for (int r = 0; r < 4; r++) {
            int row = m0 + wm + mi*16 + fq*4 + r;
            #pragma unroll
            for (int ni = 0; ni < 4; ni++) {
                int col = n0 + wn + ni*16 + fm;
                obuf[(size_t)row * CD + col] = acc[mi][ni][r];
            }
        }
    }
}

// ---------------- combine: out[t] = w0*o[s0] + w1*o[s1] + o[shared] ----------------
__global__ __launch_bounds__(256) void k_comb(
    const float* __restrict__ obuf, const int* __restrict__ islot,
    const float* __restrict__ topw, const int* __restrict__ offs,
    float* __restrict__ out)
{
    const int t = blockIdx.x;
    const int c = threadIdx.x * 4;
    const int s0 = islot[t*2], s1 = islot[t*2+1];
    const float w0 = topw[t*2], w1 = topw[t*2+1];
    const int sh = offs[8] + t;
    float4 a = *(const float4*)(obuf + (size_t)s0 * CD + c);
    float4 b = *(const float4*)(obuf + (size_t)s1 * CD + c);
    float4 s = *(const float4*)(obuf + (size_t)sh * CD + c);
    float4 o;
    o.x = fmaf(w0, a.x, fmaf(w1, b.x, s.x));
    o.y = fmaf(w0, a.y, fmaf(w1, b.y, s.y));
    o.z = fmaf(w0, a.z, fmaf(w1, b.z, s.z));
    o.w = fmaf(w0, a.w, fmaf(w1, b.w, s.w));
    *(float4*)(out + (size_t)t * CD + c) = o;
}

// ---------------- aux loss ----------------
__global__ void k_aux(const int* __restrict__ cnt, const float* __restrict__ psum,
                      float* __restrict__ out_aux) {
    if (threadIdx.x == 0 && blockIdx.x == 0) {
        float a = 0.f;
        for (int e = 0; e < 8; e++) {
            float f = (float)cnt[e] / ((float)TK * 2.f);
            float p = psum[e] / (float)TK;
            a += f * p;
        }
        out_aux[0] = 8.f * a;
    }
}

extern "C" void kernel_launch(void* const* d_in, const int* in_sizes, int n_in,
                              void* d_out, int out_size, void* d_ws, size_t ws_size,
                              hipStream_t stream) {
    const float* x  = (const float*)d_in[0];
    const float* rw = (const float*)d_in[1];
    const float* wg = (const float*)d_in[2];
    const float* wu = (const float*)d_in[3];
    const float* wd = (const float*)d_in[4];
    const float* sg = (const float*)d_in[5];
    const float* su = (const float*)d_in[6];
    const float* sd = (const float*)d_in[7];
    float* out = (float*)d_out;

    char* ws = (char*)d_ws;
    f16* xb   = (f16*)(ws + WS_XB);
    f16* hbuf = (f16*)(ws + WS_H);
    f16* wgt  = (f16*)(ws + WS_WGT);
    f16* wut  = (f16*)(ws + WS_WUT);
    f16* wdt  = (f16*)(ws + WS_WDT);
    f16* sgt  = (f16*)(ws + WS_SGT);
    f16* sut  = (f16*)(ws + WS_SUT);
    f16* sdt  = (f16*)(ws + WS_SDT);
    float* obuf = (float*)(ws + WS_OBUF);
    char* ct  = ws + WS_CT;
    int*   stok = (int*)  (ct + CT_STOK);
    float* swt  = (float*)(ct + CT_SW);
    int*   topi = (int*)  (ct + CT_TI);
    float* topw = (float*)(ct + CT_TW);
    int*   isl  = (int*)  (ct + CT_ISL);
    int*   cnt  = (int*)  (ct + CT_CNT);
    float* psum = (float*)(ct + CT_PS);
    int*   cur  = (int*)  (ct + CT_CUR);
    int*   offs = (int*)  (ct + CT_OFF);

    hipMemsetAsync(ct, 0, CT_SIZE, stream);

    k_router<<<dim3(TK / 4), dim3(256), 0, stream>>>(x, rw, xb, topi, topw, cnt, psum);
    k_prefix<<<dim3(1), dim3(64), 0, stream>>>(cnt, cur, offs);
    k_scatter<<<dim3(TK / 256), dim3(256), 0, stream>>>(topi, topw, cur, offs, stok, swt, isl);

    // weight convert+transpose, grid.z = 8 experts + 1 shared slab
    k_tr<<<dim3(HP/128, CD/64, 9), dim3(256), 0, stream>>>(
        wg, wgt, sg, sgt, CD, HD, CD, HP, 8, (size_t)CD*HD, (size_t)HP*CD);
    k_tr<<<dim3(HP/128, CD/64, 9), dim3(256), 0, stream>>>(
        wu, wut, su, sut, CD, HD, CD, HP, 8, (size_t)CD*HD, (size_t)HP*CD);
    k_tr<<<dim3(CD/128, HP/64, 9), dim3(256), 0, stream>>>(
        wd, wdt, sd, sdt, HD, CD, HP, CD, 8, (size_t)HD*CD, (size_t)CD*HP);

    k_ffn1<<<dim3(HP/128, MT), dim3(256), 0, stream>>>(xb, wgt, wut, sgt, sut, offs, cnt, stok, hbuf);
    k_ffn2<<<dim3(CD/128, MT), dim3(256), 0, stream>>>(hbuf, wdt, sdt, offs, cnt, obuf);
    k_comb<<<dim3(TK), dim3(256), 0, stream>>>(obuf, isl, topw, offs, out);
    k_aux<<<dim3(1), dim3(64), 0, stream>>>(cnt, psum, out + (size_t)TK * CD);
}